// Round 2
// baseline (121.871 us; speedup 1.0000x reference)
//
#include <hip/hip_runtime.h>
#include <stdint.h>

// ConvMemory fused: out = (3x3 conv of E=exp(x), weights=memory) / (3x3 boxsum of channel-sum(E))
// Zero-padding before softmax => OOB taps contribute exp(0)=1 to num & denom.
// Single main kernel: staging reads x (NCHW f32) directly, computes exp in-register,
// packs bf16 channel-pairs into the XOR-granule LDS halo layout, derives S by
// re-summing the rounded bf16 values (numerically consistent), then runs the
// verified implicit-GEMM MFMA K-loop (mfma_f32_32x32x16_bf16, 3-deep prefetch).

#define Cn 64
#define Hn 128
#define Wn 128
#define OC 128
#define HW (Hn * Wn)

typedef __attribute__((ext_vector_type(8))) short bf16x8_t;
typedef __attribute__((ext_vector_type(16))) float f32x16_t;

__device__ inline unsigned short f2bf(float f) {
    union { float f; uint32_t u; } v; v.f = f;
    uint32_t u = v.u;
    u += 0x7fffu + ((u >> 16) & 1u);
    return (unsigned short)(u >> 16);
}
__device__ inline float bf_lo(uint32_t u) {
    union { uint32_t u; float f; } v; v.u = u << 16;
    return v.f;
}
__device__ inline float bf_hi(uint32_t u) {
    union { uint32_t u; float f; } v; v.u = u & 0xffff0000u;
    return v.f;
}

// ---------------------------------------------------------------------------
// prep: memory[576][128] f32 -> Bt2 bf16 chunks: chunk cid=(kc*2+hi), 128 n's,
// 16B per n = 8 channels c = (kc&3)*16 + hi*8 + j, q = kc>>2 (kh*3+kw).
// ---------------------------------------------------------------------------
__global__ void prep_b2(const float* __restrict__ mem, uint4* __restrict__ Bt2) {
    int u = blockIdx.x * 256 + threadIdx.x;   // 0..9215
    int n = u & 127;
    int cid = u >> 7;                         // 0..71
    int hi = cid & 1;
    int kc = cid >> 1;                        // 0..35
    int q = kc >> 2, cblk = kc & 3;
    unsigned short h8[8];
#pragma unroll
    for (int j = 0; j < 8; j++) {
        int c = cblk * 16 + hi * 8 + j;
        h8[j] = f2bf(mem[(c * 9 + q) * OC + n]);
    }
    Bt2[cid * 128 + n] = *(const uint4*)h8;
}

// ---------------------------------------------------------------------------
// convf: 256 threads, 16x16 output tile (M=pixels 256, all 128 n_out).
// Stage A: core 16-wide aligned rows as float4 channel-pair reads -> exp ->
//   bf16 pack -> ds_write_b32 into granule slot = g ^ (p&7).
// Stage B: halo edge columns (px 0,17), scalar channel-pair reads.
// Stage C: Sh[p] = sum of the 64 stored bf16 values (slot-rotated b128 reads).
// Then Zinv boxsum and the verified MFMA K-loop + epilogue (unchanged).
// ---------------------------------------------------------------------------
__global__ __launch_bounds__(256, 2) void convf(const float* __restrict__ x,
                                                const uint4* __restrict__ Bt2,
                                                float* __restrict__ out) {
    __shared__ __align__(16) uint4 EtL[324 * 8];   // 41472 B, [p][slot]
    __shared__ float Sh[324];
    __shared__ float Zt[256];

    int bid = blockIdx.x;            // 512 = 8 b * 8 ty * 8 tx
    int b = bid >> 6;
    int ty = (bid >> 3) & 7, tx = bid & 7;
    int h0 = ty * 16, w0 = tx * 16;
    int t = threadIdx.x;
    uint32_t* Lu = (uint32_t*)EtL;

    const float* xb = x + (size_t)b * Cn * HW;

    // ---- stage A: core pixels (halo px 1..16), items = cp*72 + py*4 + qx ----
#pragma unroll
    for (int i = 0; i < 9; i++) {
        int u = i * 256 + t;          // 0..2303
        int qx = u & 3;
        int w2 = u >> 2;              // cp*18 + py
        int py = w2 % 18;
        int cp = w2 / 18;             // channel pair 0..31
        int gy = h0 - 1 + py;
        int g = cp >> 2, jj = cp & 3;
        int pb = py * 18 + 1 + qx * 4;
        uint32_t pk0, pk1, pk2, pk3;
        if (gy >= 0 && gy < Hn) {
            const float* r0 = xb + (size_t)(2 * cp) * HW + gy * Wn + w0 + qx * 4;
            float4 v0 = *(const float4*)r0;          // channel 2cp, 4 px
            float4 v1 = *(const float4*)(r0 + HW);   // channel 2cp+1
            pk0 = (uint32_t)f2bf(__expf(v0.x)) | ((uint32_t)f2bf(__expf(v1.x)) << 16);
            pk1 = (uint32_t)f2bf(__expf(v0.y)) | ((uint32_t)f2bf(__expf(v1.y)) << 16);
            pk2 = (uint32_t)f2bf(__expf(v0.z)) | ((uint32_t)f2bf(__expf(v1.z)) << 16);
            pk3 = (uint32_t)f2bf(__expf(v0.w)) | ((uint32_t)f2bf(__expf(v1.w)) << 16);
        } else {
            pk0 = pk1 = pk2 = pk3 = 0x3F803F80u;     // exp(0)=1 halo rows
        }
        Lu[(pb + 0) * 32 + (((g ^ ((pb + 0) & 7)) << 2) | jj)] = pk0;
        Lu[(pb + 1) * 32 + (((g ^ ((pb + 1) & 7)) << 2) | jj)] = pk1;
        Lu[(pb + 2) * 32 + (((g ^ ((pb + 2) & 7)) << 2) | jj)] = pk2;
        Lu[(pb + 3) * 32 + (((g ^ ((pb + 3) & 7)) << 2) | jj)] = pk3;
    }

    // ---- stage B: edge columns (halo px 0 and 17) ----
#pragma unroll
    for (int i = 0; i < 5; i++) {
        int u = i * 256 + t;
        if (u < 1152) {               // cp*36 + py*2 + side
            int side = u & 1;
            int v = u >> 1;
            int py = v % 18;
            int cp = v / 18;
            int gy = h0 - 1 + py;
            int gx = side ? (w0 + 16) : (w0 - 1);
            int p = py * 18 + side * 17;
            int g = cp >> 2, jj = cp & 3;
            uint32_t pk;
            if (gy >= 0 && gy < Hn && gx >= 0 && gx < Wn) {
                const float* r0 = xb + (size_t)(2 * cp) * HW + gy * Wn + gx;
                pk = (uint32_t)f2bf(__expf(r0[0])) | ((uint32_t)f2bf(__expf(r0[HW])) << 16);
            } else {
                pk = 0x3F803F80u;
            }
            Lu[p * 32 + (((g ^ (p & 7)) << 2) | jj)] = pk;
        }
    }
    __syncthreads();

    // ---- stage C: Sh[p] = sum over 64 channels of stored (rounded) bf16 ----
#pragma unroll
    for (int pi = 0; pi < 2; pi++) {
        int p = pi * 256 + t;
        if (p < 324) {
            float s = 0.f;
#pragma unroll
            for (int k = 0; k < 8; k++) {
                uint4 q = EtL[p * 8 + ((k + t) & 7)];   // slot-rotated, all 8 granules
                s += bf_lo(q.x) + bf_hi(q.x) + bf_lo(q.y) + bf_hi(q.y)
                   + bf_lo(q.z) + bf_hi(q.z) + bf_lo(q.w) + bf_hi(q.w);
            }
            Sh[p] = s;    // OOB pixels: all-ones granules -> 64.0 automatically
        }
    }
    __syncthreads();

    // ---- Zinv per output pixel ----
    {
        int zy = t >> 4, zx = t & 15;
        float z = 0.f;
#pragma unroll
        for (int dy = 0; dy < 3; dy++)
#pragma unroll
            for (int dx = 0; dx < 3; dx++)
                z += Sh[(zy + dy) * 18 + (zx + dx)];
        Zt[t] = 1.0f / z;
    }
    __syncthreads();

    // ---- MFMA K-loop: 36 chunks of K=16, 3-deep prefetch (verbatim) ----
    int lane = t & 63, wv = t >> 6;
    int l31 = lane & 31, hi = lane >> 5;
    int x0v = l31 & 15;
    int y0[2];
    y0[0] = (wv * 2 + 0) * 2 + (l31 >> 4);
    y0[1] = (wv * 2 + 1) * 2 + (l31 >> 4);

    f32x16_t acc[2][4];
#pragma unroll
    for (int j = 0; j < 2; j++)
#pragma unroll
        for (int g = 0; g < 4; g++)
#pragma unroll
            for (int r = 0; r < 16; r++) acc[j][g][r] = 0.f;

    bf16x8_t Wf[3][4], Ef[3][2];

    auto loadW = [&](int kc, int s) {
        const uint4* bp = Bt2 + (size_t)((kc * 2 + hi) * 128 + l31);
#pragma unroll
        for (int g = 0; g < 4; g++)
            Wf[s][g] = *(const bf16x8_t*)(bp + g * 32);
    };
    auto loadE = [&](int kc, int s) {
        int q = kc >> 2, cblk = kc & 3;
        int kh = q / 3, kw = q - kh * 3;
        int g = cblk * 2 + hi;
#pragma unroll
        for (int j = 0; j < 2; j++) {
            int pix = (y0[j] + kh) * 18 + (x0v + kw);
            Ef[s][j] = *(const bf16x8_t*)&EtL[pix * 8 + (g ^ (pix & 7))];
        }
    };

    loadW(0, 0); loadE(0, 0);
    loadW(1, 1); loadE(1, 1);
    loadW(2, 2); loadE(2, 2);
#pragma unroll
    for (int kc = 0; kc < 36; kc++) {
        int s = kc % 3;
#pragma unroll
        for (int g = 0; g < 4; g++)
#pragma unroll
            for (int j = 0; j < 2; j++)
                acc[j][g] = __builtin_amdgcn_mfma_f32_32x32x16_bf16(
                    Wf[s][g], Ef[s][j], acc[j][g], 0, 0, 0);
        if (kc + 3 < 36) { loadW(kc + 3, s); loadE(kc + 3, s); }
    }

    // ---- epilogue: D col(n)=pixel=l31, row m=n_out=(r&3)+8*(r>>2)+4*hi ----
#pragma unroll
    for (int j = 0; j < 2; j++) {
        float zi = Zt[(wv * 2 + j) * 32 + l31];
        float* ob = out + (size_t)b * OC * HW + (h0 + y0[j]) * Wn + (w0 + x0v)
                  + (size_t)(4 * hi) * HW;
#pragma unroll
        for (int g = 0; g < 4; g++) {
#pragma unroll
            for (int r = 0; r < 16; r++) {
                int nrel = g * 32 + (r & 3) + 8 * (r >> 2);   // + 4*hi in ob
                ob[(size_t)nrel * HW] = acc[j][g][r] * zi;
            }
        }
    }
}

// ---------------------------------------------------------------------------
extern "C" void kernel_launch(void* const* d_in, const int* in_sizes, int n_in,
                              void* d_out, int out_size, void* d_ws, size_t ws_size,
                              hipStream_t stream) {
    const float* x = (const float*)d_in[0];
    const float* mem = (const float*)d_in[1];
    float* out = (float*)d_out;

    uint4* Bt2 = (uint4*)d_ws;                 // 147,456 B

    prep_b2<<<36, 256, 0, stream>>>(mem, Bt2);
    convf<<<512, 256, 0, stream>>>(x, Bt2, out);
}

// Round 3
// 112.409 us; speedup vs baseline: 1.0842x; 1.0842x over previous
//
#include <hip/hip_runtime.h>
#include <stdint.h>

// ConvMemory fused v3: out = (3x3 conv of E=exp(x), W=memory) / (3x3 boxsum of chan-sum(E))
// 8x16 tile, 1024 blocks (XCD-chunk swizzled), 512 threads = 8 waves.
// Wave = 64 px (2 j-tiles of 32) x 32 oc  -> acc[2] f32x16 (32 regs), fits 4 waves/SIMD.
// Staging: granule-owning threads (8 ch x 4 px), all-float4 aligned reads incl. edge
// groups; conflict-free b128 LDS writes with swizzle slot = g ^ ((p>>1)&7).
// S = sum of rounded bf16 LDS values (numerics identical to verified version).

#define Cn 64
#define Hn 128
#define Wn 128
#define OC 128
#define HW (Hn * Wn)

typedef __attribute__((ext_vector_type(8))) short bf16x8_t;
typedef __attribute__((ext_vector_type(16))) float f32x16_t;

__device__ inline unsigned short f2bf(float f) {
    union { float f; uint32_t u; } v; v.f = f;
    uint32_t u = v.u;
    u += 0x7fffu + ((u >> 16) & 1u);
    return (unsigned short)(u >> 16);
}
__device__ inline float bf_lo(uint32_t u) {
    union { uint32_t u; float f; } v; v.u = u << 16;
    return v.f;
}
__device__ inline float bf_hi(uint32_t u) {
    union { uint32_t u; float f; } v; v.u = u & 0xffff0000u;
    return v.f;
}

// ---------------------------------------------------------------------------
// prep: memory[576][128] f32 -> Bt2 bf16 chunks: chunk cid=(kc*2+hi), 128 n's,
// 16B per n = 8 channels c = (kc&3)*16 + hi*8 + j, q = kc>>2 (kh*3+kw).
// ---------------------------------------------------------------------------
__global__ void prep_b2(const float* __restrict__ mem, uint4* __restrict__ Bt2) {
    int u = blockIdx.x * 256 + threadIdx.x;   // 0..9215
    int n = u & 127;
    int cid = u >> 7;                         // 0..71
    int hi = cid & 1;
    int kc = cid >> 1;                        // 0..35
    int q = kc >> 2, cblk = kc & 3;
    unsigned short h8[8];
#pragma unroll
    for (int j = 0; j < 8; j++) {
        int c = cblk * 16 + hi * 8 + j;
        h8[j] = f2bf(mem[(c * 9 + q) * OC + n]);
    }
    Bt2[cid * 128 + n] = *(const uint4*)h8;
}

// ---------------------------------------------------------------------------
__global__ __launch_bounds__(512, 4) void convf(const float* __restrict__ x,
                                                const uint4* __restrict__ Bt2,
                                                float* __restrict__ out) {
    __shared__ __align__(16) uint4 EtL[180 * 8];   // 23040 B, [p][slot], 10x18 halo
    __shared__ float Sh[180];
    __shared__ float Zt[128];

    int bid0 = blockIdx.x;
    int bid = ((bid0 & 7) << 7) | (bid0 >> 3);   // XCD chunk swizzle, 1024 = 8*128
    int b = bid >> 7;                            // 1024 = 8 b * 16 ty * 8 tx
    int ty = (bid >> 3) & 15, tx = bid & 7;
    int h0 = ty * 8, w0 = tx * 16;
    int t = threadIdx.x;

    const float* xb = x + (size_t)b * Cn * HW;
    const uint4 PAD = make_uint4(0x3F803F80u, 0x3F803F80u, 0x3F803F80u, 0x3F803F80u);

    // ---- stage: 480 items = g(8) x py(10) x qs(6); thread owns 8 ch x (4|1) px ----
    if (t < 480) {
        int qs = t % 6;
        int v6 = t / 6;
        int py = v6 % 10;
        int g  = v6 / 10;                 // granule 0..7 = channels 8g..8g+7
        int gy = h0 - 1 + py;
        bool inrow = (gy >= 0) & (gy < Hn);
        int xg = w0 - 4 + qs * 4;         // qs=0: w0-4 | qs1..4: core | qs=5: w0+16
        const float* base = xb + (size_t)(8 * g) * HW + (size_t)gy * Wn + xg;

        if (qs >= 1 && qs <= 4) {         // core: 4 px, columns p_x = (qs-1)*4+1 .. +4
            if (inrow) {
                float4 v[8];
#pragma unroll
                for (int k = 0; k < 8; k++)
                    v[k] = *(const float4*)(base + (size_t)k * HW);
#pragma unroll
                for (int i = 0; i < 4; i++) {
                    uint32_t wd[4];
#pragma unroll
                    for (int j = 0; j < 4; j++) {
                        float a = ((const float*)&v[2 * j])[i];
                        float c = ((const float*)&v[2 * j + 1])[i];
                        wd[j] = (uint32_t)f2bf(__expf(a)) | ((uint32_t)f2bf(__expf(c)) << 16);
                    }
                    int p = py * 18 + (qs - 1) * 4 + 1 + i;
                    EtL[p * 8 + (g ^ ((p >> 1) & 7))] = *(const uint4*)wd;
                }
            } else {
#pragma unroll
                for (int i = 0; i < 4; i++) {
                    int p = py * 18 + (qs - 1) * 4 + 1 + i;
                    EtL[p * 8 + (g ^ ((p >> 1) & 7))] = PAD;
                }
            }
        } else {                          // edge: 1 px, p_x = 0 (qs=0) or 17 (qs=5)
            int side = (qs == 5);
            int p = py * 18 + (side ? 17 : 0);
            bool real = inrow && (side ? (tx < 7) : (tx > 0));
            uint4 gran = PAD;
            if (real) {
                float4 v[8];
#pragma unroll
                for (int k = 0; k < 8; k++)
                    v[k] = *(const float4*)(base + (size_t)k * HW);
                uint32_t wd[4];
#pragma unroll
                for (int j = 0; j < 4; j++) {
                    float a = side ? ((const float*)&v[2 * j])[0]     : ((const float*)&v[2 * j])[3];
                    float c = side ? ((const float*)&v[2 * j + 1])[0] : ((const float*)&v[2 * j + 1])[3];
                    wd[j] = (uint32_t)f2bf(__expf(a)) | ((uint32_t)f2bf(__expf(c)) << 16);
                }
                gran = *(const uint4*)wd;
            }
            EtL[p * 8 + (g ^ ((p >> 1) & 7))] = gran;
        }
    }
    __syncthreads();

    // ---- Sh[p] = sum of 64 stored bf16 (slot-rotated, conflict-free) ----
    if (t < 180) {
        float s = 0.f;
#pragma unroll
        for (int k = 0; k < 8; k++) {
            uint4 q = EtL[t * 8 + ((k + t) & 7)];
            s += bf_lo(q.x) + bf_hi(q.x) + bf_lo(q.y) + bf_hi(q.y)
               + bf_lo(q.z) + bf_hi(q.z) + bf_lo(q.w) + bf_hi(q.w);
        }
        Sh[t] = s;    // OOB pixels: all-ones granules -> 64.0 automatically
    }
    __syncthreads();

    // ---- Zinv per output pixel (128 px) ----
    if (t < 128) {
        int zy = t >> 4, zx = t & 15;
        float z = 0.f;
#pragma unroll
        for (int dy = 0; dy < 3; dy++)
#pragma unroll
            for (int dx = 0; dx < 3; dx++)
                z += Sh[(zy + dy) * 18 + (zx + dx)];
        Zt[t] = 1.0f / z;
    }
    __syncthreads();

    // ---- MFMA K-loop: wave = 64 px x 32 oc; 36 chunks of K=16, 3-deep prefetch ----
    int lane = t & 63;
    int wid = t >> 6;                 // 0..7
    int wo = wid & 3;                 // oc 32-block
    int wp = wid >> 2;                // px-pair 0..1
    int l31 = lane & 31, hi = lane >> 5;
    int x0v = l31 & 15;
    int y0[2];
    y0[0] = (wp * 2 + 0) * 2 + (l31 >> 4);
    y0[1] = (wp * 2 + 1) * 2 + (l31 >> 4);

    f32x16_t acc[2];
#pragma unroll
    for (int j = 0; j < 2; j++)
#pragma unroll
        for (int r = 0; r < 16; r++) acc[j][r] = 0.f;

    bf16x8_t Wf[3], Ef[3][2];

    auto loadW = [&](int kc, int s) {
        Wf[s] = *(const bf16x8_t*)(Bt2 + (size_t)((kc * 2 + hi) * 128 + wo * 32 + l31));
    };
    auto loadE = [&](int kc, int s) {
        int q = kc >> 2, cblk = kc & 3;
        int kh = q / 3, kw = q - kh * 3;
        int ge = cblk * 2 + hi;
#pragma unroll
        for (int j = 0; j < 2; j++) {
            int pix = (y0[j] + kh) * 18 + (x0v + kw);
            Ef[s][j] = *(const bf16x8_t*)&EtL[pix * 8 + (ge ^ ((pix >> 1) & 7))];
        }
    };

    loadW(0, 0); loadE(0, 0);
    loadW(1, 1); loadE(1, 1);
    loadW(2, 2); loadE(2, 2);
#pragma unroll
    for (int kc = 0; kc < 36; kc++) {
        int s = kc % 3;
#pragma unroll
        for (int j = 0; j < 2; j++)
            acc[j] = __builtin_amdgcn_mfma_f32_32x32x16_bf16(
                Wf[s], Ef[s][j], acc[j], 0, 0, 0);
        if (kc + 3 < 36) { loadW(kc + 3, s); loadE(kc + 3, s); }
    }

    // ---- epilogue: D col(n)=pixel=l31, row m=(r&3)+8*(r>>2)+4*hi, oc=wo*32+m ----
#pragma unroll
    for (int j = 0; j < 2; j++) {
        float zi = Zt[(y0[j] << 4) | x0v];
        float* ob = out + (size_t)b * OC * HW + (size_t)(wo * 32 + 4 * hi) * HW
                  + (h0 + y0[j]) * Wn + (w0 + x0v);
#pragma unroll
        for (int r = 0; r < 16; r++) {
            int nrel = (r & 3) + 8 * (r >> 2);   // + 4*hi folded into ob
            ob[(size_t)nrel * HW] = acc[j][r] * zi;
        }
    }
}

// ---------------------------------------------------------------------------
extern "C" void kernel_launch(void* const* d_in, const int* in_sizes, int n_in,
                              void* d_out, int out_size, void* d_ws, size_t ws_size,
                              hipStream_t stream) {
    const float* x = (const float*)d_in[0];
    const float* mem = (const float*)d_in[1];
    float* out = (float*)d_out;

    uint4* Bt2 = (uint4*)d_ws;                 // 147,456 B

    prep_b2<<<36, 256, 0, stream>>>(mem, Bt2);
    convf<<<1024, 512, 0, stream>>>(x, Bt2, out);
}